// Round 8
// baseline (1586.349 us; speedup 1.0000x reference)
//
#include <hip/hip_runtime.h>
#include <stdint.h>
#include <stdio.h>

#define NOUT 512
#define NSEG 1024

typedef unsigned short u16;
typedef __attribute__((ext_vector_type(4))) float f32x4;
typedef __attribute__((ext_vector_type(8))) short s16x8;
typedef __attribute__((ext_vector_type(4))) unsigned short u16x4;

__device__ __forceinline__ u16 f2b(float f) {
  union { float f; uint32_t u; } v; v.f = f;
  uint32_t r = v.u + 0x7FFFu + ((v.u >> 16) & 1u);
  return (u16)(r >> 16);
}
__device__ __forceinline__ float b2f(u16 b) {
  union { uint32_t u; float f; } v; v.u = ((uint32_t)b) << 16;
  return v.f;
}

// ---------------- cast kernels ----------------
__global__ void k_cast(const float* __restrict__ src, u16* __restrict__ dst, long n4) {
  long i = blockIdx.x * (long)blockDim.x + threadIdx.x;
  long stride = (long)gridDim.x * blockDim.x;
  for (; i < n4; i += stride) {
    float4 v = reinterpret_cast<const float4*>(src)[i];
    u16x4 o;
    o.x = f2b(v.x); o.y = f2b(v.y); o.z = f2b(v.z); o.w = f2b(v.w);
    reinterpret_cast<u16x4*>(dst)[i] = o;
  }
}

// w: [K][512] f32 -> out: [512][K] bf16 (B^T), coalesced both sides via LDS tile
__global__ void k_wtcastT(const float* __restrict__ w, u16* __restrict__ out, int K) {
  __shared__ float tile[32][33];
  int k0 = blockIdx.x * 32, c0 = blockIdx.y * 32;
  int t = threadIdx.x;  // 256
  int rr = t >> 5, cc = t & 31;
#pragma unroll
  for (int p = 0; p < 4; ++p)
    tile[p * 8 + rr][cc] = w[(long)(k0 + p * 8 + rr) * NOUT + c0 + cc];
  __syncthreads();
#pragma unroll
  for (int p = 0; p < 4; ++p)
    out[(long)(c0 + p * 8 + rr) * K + k0 + cc] = f2b(tile[cc][p * 8 + rr]);
}

// ---------------- segment sort ----------------
__global__ void k_hist(const int* __restrict__ ele, int* __restrict__ cnt, int N) {
  int i = blockIdx.x * blockDim.x + threadIdx.x;
  int stride = gridDim.x * blockDim.x;
  for (; i < N; i += stride) atomicAdd(&cnt[ele[i]], 1);
}

__global__ void k_scan(const int* __restrict__ cnt, int* __restrict__ off) {
  __shared__ int tmp[NSEG];
  int t = threadIdx.x;
  tmp[t] = cnt[t];
  __syncthreads();
  for (int o = 1; o < NSEG; o <<= 1) {
    int add = (t >= o) ? tmp[t - o] : 0;
    __syncthreads();
    tmp[t] += add;
    __syncthreads();
  }
  off[t] = tmp[t] - cnt[t];
}

__global__ void k_scatter(const int* __restrict__ ele, const int* __restrict__ off,
                          int* __restrict__ fill, int* __restrict__ rows, int N) {
  int i = blockIdx.x * blockDim.x + threadIdx.x;
  int stride = gridDim.x * blockDim.x;
  for (; i < N; i += stride) {
    int e = ele[i];
    int p = atomicAdd(&fill[e], 1);
    rows[off[e] + p] = i;
  }
}

// ---------------- BN finalize ----------------
__global__ void k_finalize(const float* __restrict__ sum, const float* __restrict__ sumsq,
                           const float* __restrict__ g, const float* __restrict__ be,
                           float* __restrict__ A, float* __restrict__ C, int M) {
  int c = threadIdx.x;  // 512
  float m = sum[c] / (float)M;
  float v = sumsq[c] / (float)M - m * m;
  float a = g[c] * rsqrtf(v + 1e-5f);
  A[c] = a;
  C[c] = be[c] - a * m;
}

// ---------------- fused BN-apply + ReLU + segment mean (4 col-quarters) ----------------
__global__ void k_bnseg(const u16* __restrict__ hp, u16* __restrict__ h, u16* __restrict__ mean,
                        const float* __restrict__ A, const float* __restrict__ C,
                        const int* __restrict__ off, const int* __restrict__ cnt,
                        const int* __restrict__ rows) {
  int s = blockIdx.x;
  int c0 = blockIdx.y * 128 + 2 * threadIdx.x;  // 64 threads -> cols c0, c0+1
  int n = cnt[s], o = off[s];
  float a0 = A[c0], a1 = A[c0 + 1], cc0 = C[c0], cc1 = C[c0 + 1];
  float s0 = 0.f, s1 = 0.f;
  for (int j = 0; j < n; ++j) {
    int r = rows[o + j];
    uint32_t v = *reinterpret_cast<const uint32_t*>(&hp[(long)r * NOUT + c0]);
    float h0 = fmaxf(a0 * b2f((u16)(v & 0xffff)) + cc0, 0.f);
    float h1 = fmaxf(a1 * b2f((u16)(v >> 16)) + cc1, 0.f);
    s0 += h0; s1 += h1;
    *reinterpret_cast<uint32_t*>(&h[(long)r * NOUT + c0]) =
        ((uint32_t)f2b(h1) << 16) | (uint32_t)f2b(h0);
  }
  float inv = 1.f / fmaxf((float)n, 1.f);
  *reinterpret_cast<uint32_t*>(&mean[(long)s * NOUT + c0]) =
      ((uint32_t)f2b(s1 * inv) << 16) | (uint32_t)f2b(s0 * inv);
}

__global__ void k_final(const u16* __restrict__ hp, float* __restrict__ out,
                        const float* __restrict__ A, const float* __restrict__ C, long n4) {
  long i = blockIdx.x * (long)blockDim.x + threadIdx.x;
  long stride = (long)gridDim.x * blockDim.x;
  for (; i < n4; i += stride) {
    u16x4 v = reinterpret_cast<const u16x4*>(hp)[i];
    int c0 = (int)((i * 4) & (NOUT - 1));
    float4 a = *reinterpret_cast<const float4*>(&A[c0]);
    float4 c = *reinterpret_cast<const float4*>(&C[c0]);
    float4 o;
    o.x = fmaxf(a.x * b2f(v.x) + c.x, 0.f);
    o.y = fmaxf(a.y * b2f(v.y) + c.y, 0.f);
    o.z = fmaxf(a.z * b2f(v.z) + c.z, 0.f);
    o.w = fmaxf(a.w * b2f(v.w) + c.w, 0.f);
    reinterpret_cast<float4*>(out)[i] = o;
  }
}

// ---------------- GEMM: C[M,512] = A[M,K] @ W[K,512] -- LDS-FREE, register-direct ----------------
// Rationale (m169 / Common-mistake #7): B panel (<=1.25MB) and hot A panel are L2/L3
// resident; the MFMA A/B fragment pattern (16 rows x 64B per load) covers cache lines
// exactly, so per-lane global_load_dwordx4 achieves full line utilization WITHOUT LDS.
// No LDS, no barriers: every wave pipelines independently; 12 waves/CU hide L2 latency.
// Template params make the K-loop fully unrolled with compile-time region selects.
// A: 2 regions (k<E0 -> p0 gather?G0 else p1 gather?G1). B: wbt [512][ldb] (=W^T),
// k += BSKIP when k>=E0B. Epilogue: optional tab[ele[r]] gather-add, bf16/f32 write,
// optional atomic col sum/sqsum (biases dropped - cancel in training-mode BN).
template <int K, int E0, int W0, int W1, int G0, int G1, int E0B, int BSKIP>
__global__ __launch_bounds__(256, 3) void k_gemm(
    const u16* __restrict__ p0, const u16* __restrict__ p1,
    const int* __restrict__ ele,
    const u16* __restrict__ wbt, int ldb,
    const float* __restrict__ tab, int addtab,
    u16* __restrict__ outp, float* __restrict__ outf, int wf32,
    float* __restrict__ csum, float* __restrict__ csq, int dostats,
    int M) {
  int nwg = gridDim.x;
  int orig = blockIdx.x;
  // bijective XCD swizzle (m204)
  int q = nwg >> 3, r8 = nwg & 7;
  int xcd = orig & 7, loc = orig >> 3;
  int bid = (xcd < r8 ? xcd * (q + 1) : r8 * (q + 1) + (xcd - r8) * q) + loc;
  int mt = bid >> 2, ct = bid & 3;  // 4 col-tiles of same mt adjacent -> L2 A reuse
  int brow = mt * 128, bcol = ct * 128;

  int tid = (int)threadIdx.x;
  int lane = tid & 63;
  int wid = tid >> 6;
  int wr = wid >> 1, wc = wid & 1;  // 2x2 waves, 64x64 each
  int l15 = lane & 15, kg = lane >> 4;

  const char* cp0 = (const char*)p0;
  const char* cp1 = (const char*)p1;
  const char* cpb = (const char*)wbt;

  // per-lane byte voffsets: A frag row = l15 + m*16 (+wave row base); k-octet = kg
  uint32_t va0[4], va1[4], vb[4];
#pragma unroll
  for (int m = 0; m < 4; ++m) {
    int r = brow + wr * 64 + m * 16 + l15;
    if (r >= M) r = M - 1;
    int e = (G0 | G1) ? ele[r] : 0;
    va0[m] = (uint32_t)((G0 ? e : r) * W0 + kg * 8) * 2u;
    va1[m] = (uint32_t)((G1 ? e : r) * W1 + kg * 8) * 2u;
  }
#pragma unroll
  for (int n = 0; n < 4; ++n)
    vb[n] = (uint32_t)((bcol + wc * 64 + n * 16 + l15) * ldb + kg * 8) * 2u;

  f32x4 acc[4][4];
#pragma unroll
  for (int m = 0; m < 4; ++m)
#pragma unroll
    for (int n = 0; n < 4; ++n)
#pragma unroll
      for (int j = 0; j < 4; ++j) acc[m][n][j] = 0.f;

#pragma unroll
  for (int t = 0; t < K / 32; ++t) {
    const int k0 = t * 32;
    s16x8 af[4], bf[4];
#pragma unroll
    for (int m = 0; m < 4; ++m) {
      if (k0 < E0)
        af[m] = *reinterpret_cast<const s16x8*>(cp0 + va0[m] + 2 * k0);
      else
        af[m] = *reinterpret_cast<const s16x8*>(cp1 + va1[m] + 2 * (k0 - E0));
    }
    const int bo = k0 + (k0 >= E0B ? BSKIP : 0);
#pragma unroll
    for (int n = 0; n < 4; ++n)
      bf[n] = *reinterpret_cast<const s16x8*>(cpb + vb[n] + 2 * bo);
#pragma unroll
    for (int m = 0; m < 4; ++m)
#pragma unroll
      for (int n = 0; n < 4; ++n)
        acc[m][n] = __builtin_amdgcn_mfma_f32_16x16x32_bf16(af[m], bf[n], acc[m][n], 0, 0, 0);
  }

  // epilogue: C layout col = lane&15, row = kg*4+j (m89-verified)
  float sums[4] = {0.f, 0.f, 0.f, 0.f}, sqs[4] = {0.f, 0.f, 0.f, 0.f};
#pragma unroll
  for (int m = 0; m < 4; ++m) {
    int row0 = brow + wr * 64 + m * 16 + kg * 4;
#pragma unroll
    for (int j = 0; j < 4; ++j) {
      int r = row0 + j;
      if (r < M) {
        long rb = (long)r * NOUT;
        long tb = addtab ? (long)ele[r] * NOUT : 0;
#pragma unroll
        for (int n = 0; n < 4; ++n) {
          int col = bcol + wc * 64 + n * 16 + l15;
          float v = acc[m][n][j];
          if (addtab) v += tab[tb + col];
          if (wf32) outf[rb + col] = v;
          else outp[rb + col] = f2b(v);
          sums[n] += v;
          sqs[n] += v * v;
        }
      }
    }
  }
  if (dostats) {
#pragma unroll
    for (int n = 0; n < 4; ++n) {
      sums[n] += __shfl_xor(sums[n], 16);
      sums[n] += __shfl_xor(sums[n], 32);
      sqs[n] += __shfl_xor(sqs[n], 16);
      sqs[n] += __shfl_xor(sqs[n], 32);
    }
    if (kg == 0) {
#pragma unroll
      for (int n = 0; n < 4; ++n) {
        int col = bcol + wc * 64 + n * 16 + l15;
        atomicAdd(&csum[col], sums[n]);
        atomicAdd(&csq[col], sqs[n]);
      }
    }
  }
}

// ---------------- host ----------------
extern "C" void kernel_launch(void* const* d_in, const int* in_sizes, int n_in,
                              void* d_out, int out_size, void* d_ws, size_t ws_size,
                              hipStream_t stream) {
  const float* x    = (const float*)d_in[0];
  const float* dist = (const float*)d_in[1];
  const int* ele    = (const int*)d_in[3];
  const float* l1w  = (const float*)d_in[4];
  const float* l1g  = (const float*)d_in[6];
  const float* l1be = (const float*)d_in[7];
  const float* l2w  = (const float*)d_in[8];
  const float* l2g  = (const float*)d_in[10];
  const float* l2be = (const float*)d_in[11];
  const float* fw   = (const float*)d_in[12];
  const float* fg   = (const float*)d_in[14];
  const float* fbe  = (const float*)d_in[15];

  int N = in_sizes[0] / 1024;  // 100000
  float* out = (float*)d_out;
  u16* xbf = (u16*)d_out;      // bf16 x overlays d_out (exact size, dead by final write)

  int MT = (N + 127) / 128;    // 782

  char* w = (char*)d_ws;
  auto alloc = [&](size_t bytes) {
    char* p = w;
    w += (bytes + 255) & ~(size_t)255;
    return p;
  };
  u16* dist_bf = (u16*)alloc((size_t)N * 256 * 2);
  u16* hp      = (u16*)alloc((size_t)N * NOUT * 2);
  u16* h       = (u16*)alloc((size_t)N * NOUT * 2);
  u16* mean    = (u16*)alloc((size_t)NSEG * NOUT * 2);
  u16* w1bt    = (u16*)alloc((size_t)NOUT * 1280 * 2);
  u16* w2bt    = (u16*)alloc((size_t)NOUT * 1280 * 2);
  u16* fbt     = (u16*)alloc((size_t)NOUT * 1024 * 2);
  float* mc2   = (float*)alloc((size_t)NSEG * NOUT * 4);
  float* mc3   = (float*)alloc((size_t)NSEG * NOUT * 4);
  float* colsum = (float*)alloc(NOUT * 4 * 2);
  float* colsumsq = colsum + NOUT;
  float* bnA   = (float*)alloc(NOUT * 4);
  float* bnC   = (float*)alloc(NOUT * 4);
  int* seg_cnt = (int*)alloc(NSEG * 4);
  int* seg_off = (int*)alloc(NSEG * 4);
  int* seg_fill = (int*)alloc(NSEG * 4);
  int* rows    = (int*)alloc((size_t)N * 4);

  size_t need = (size_t)(w - (char*)d_ws);
  if (need > ws_size) {
    fprintf(stderr, "kernel_launch: ws too small: need %zu have %zu\n", need, ws_size);
    return;
  }

  long n4x = (long)N * 1024 / 4;
  long n4d = (long)N * 256 / 4;
  long n4h = (long)N * NOUT / 4;
  int gemmGrid = MT * 4;          // 3128
  int mcGrid = (NSEG / 128) * 4;  // 32
  dim3 bnsegGrid(NSEG, 4);

  // casts
  k_cast<<<4096, 256, 0, stream>>>(x, xbf, n4x);
  k_cast<<<2048, 256, 0, stream>>>(dist, dist_bf, n4d);
  dim3 wt1(1280 / 32, 16), wt3(1024 / 32, 16);
  k_wtcastT<<<wt1, 256, 0, stream>>>(l1w, w1bt, 1280);
  k_wtcastT<<<wt1, 256, 0, stream>>>(l2w, w2bt, 1280);
  k_wtcastT<<<wt3, 256, 0, stream>>>(fw, fbt, 1024);

  // segment sort
  hipMemsetAsync(seg_cnt, 0, NSEG * 4, stream);
  hipMemsetAsync(seg_fill, 0, NSEG * 4, stream);
  k_hist<<<512, 256, 0, stream>>>(ele, seg_cnt, N);
  k_scan<<<1, NSEG, 0, stream>>>(seg_cnt, seg_off);
  k_scatter<<<512, 256, 0, stream>>>(ele, seg_off, seg_fill, rows, N);

  // ---- layer 1: A = [x(1024) | dist(256)], K=1280 ----
  hipMemsetAsync(colsum, 0, NOUT * 4 * 2, stream);
  k_gemm<1280, 1024, 1024, 256, 0, 0, 1280, 0><<<gemmGrid, 256, 0, stream>>>(
      xbf, dist_bf, ele, w1bt, 1280, mc2, 0, hp, mc2, 0, colsum, colsumsq, 1, N);
  k_finalize<<<1, NOUT, 0, stream>>>(colsum, colsumsq, l1g, l1be, bnA, bnC, N);
  k_bnseg<<<bnsegGrid, 64, 0, stream>>>(hp, h, mean, bnA, bnC, seg_off, seg_cnt, rows);

  // ---- layer 2: mc2 = mean @ W2[512:1024); A = [h(512) | dist(256)], K=768 ----
  k_gemm<512, 512, 512, 512, 0, 0, 512, 0><<<mcGrid, 256, 0, stream>>>(
      mean, mean, ele, w2bt + 512, 1280, mc2, 0, hp, mc2, 1, colsum, colsumsq, 0, NSEG);
  hipMemsetAsync(colsum, 0, NOUT * 4 * 2, stream);
  k_gemm<768, 512, 512, 256, 0, 0, 512, 512><<<gemmGrid, 256, 0, stream>>>(
      h, dist_bf, ele, w2bt, 1280, mc2, 1, hp, mc2, 0, colsum, colsumsq, 1, N);
  k_finalize<<<1, NOUT, 0, stream>>>(colsum, colsumsq, l2g, l2be, bnA, bnC, N);
  k_bnseg<<<bnsegGrid, 64, 0, stream>>>(hp, h, mean, bnA, bnC, seg_off, seg_cnt, rows);

  // ---- final layer: mc3 = mean @ F[512:1024); A = h, K=512 ----
  k_gemm<512, 512, 512, 512, 0, 0, 512, 0><<<mcGrid, 256, 0, stream>>>(
      mean, mean, ele, fbt + 512, 1024, mc3, 0, hp, mc3, 1, colsum, colsumsq, 0, NSEG);
  hipMemsetAsync(colsum, 0, NOUT * 4 * 2, stream);
  k_gemm<512, 512, 512, 512, 0, 0, 512, 0><<<gemmGrid, 256, 0, stream>>>(
      h, h, ele, fbt, 1024, mc3, 1, hp, mc3, 0, colsum, colsumsq, 1, N);
  k_finalize<<<1, NOUT, 0, stream>>>(colsum, colsumsq, fg, fbe, bnA, bnC, N);
  k_final<<<4096, 256, 0, stream>>>(hp, out, bnA, bnC, n4h);
}

// Round 9
// 951.164 us; speedup vs baseline: 1.6678x; 1.6678x over previous
//
#include <hip/hip_runtime.h>
#include <stdint.h>
#include <stdio.h>

#define NOUT 512
#define NSEG 1024

typedef unsigned short u16;
typedef __attribute__((ext_vector_type(4))) float f32x4;
typedef __attribute__((ext_vector_type(8))) short s16x8;
typedef __attribute__((ext_vector_type(4))) unsigned short u16x4;

__device__ __forceinline__ u16 f2b(float f) {
  union { float f; uint32_t u; } v; v.f = f;
  uint32_t r = v.u + 0x7FFFu + ((v.u >> 16) & 1u);
  return (u16)(r >> 16);
}
__device__ __forceinline__ float b2f(u16 b) {
  union { uint32_t u; float f; } v; v.u = ((uint32_t)b) << 16;
  return v.f;
}

typedef __attribute__((address_space(1))) const void GAS;
typedef __attribute__((address_space(3))) void LAS;
__device__ __forceinline__ void llds16(const void* g, void* l) {
  __builtin_amdgcn_global_load_lds((GAS*)g, (LAS*)l, 16, 0, 0);
}

// ---------------- cast kernels ----------------
__global__ void k_cast(const float* __restrict__ src, u16* __restrict__ dst, long n4) {
  long i = blockIdx.x * (long)blockDim.x + threadIdx.x;
  long stride = (long)gridDim.x * blockDim.x;
  for (; i < n4; i += stride) {
    float4 v = reinterpret_cast<const float4*>(src)[i];
    u16x4 o;
    o.x = f2b(v.x); o.y = f2b(v.y); o.z = f2b(v.z); o.w = f2b(v.w);
    reinterpret_cast<u16x4*>(dst)[i] = o;
  }
}

// w: [K][512] f32 -> out: [512][K] bf16 (B^T), coalesced both sides via LDS tile
__global__ void k_wtcastT(const float* __restrict__ w, u16* __restrict__ out, int K) {
  __shared__ float tile[32][33];
  int k0 = blockIdx.x * 32, c0 = blockIdx.y * 32;
  int t = threadIdx.x;  // 256
  int rr = t >> 5, cc = t & 31;
#pragma unroll
  for (int p = 0; p < 4; ++p)
    tile[p * 8 + rr][cc] = w[(long)(k0 + p * 8 + rr) * NOUT + c0 + cc];
  __syncthreads();
#pragma unroll
  for (int p = 0; p < 4; ++p)
    out[(long)(c0 + p * 8 + rr) * K + k0 + cc] = f2b(tile[cc][p * 8 + rr]);
}

// ---------------- segment sort ----------------
__global__ void k_hist(const int* __restrict__ ele, int* __restrict__ cnt, int N) {
  int i = blockIdx.x * blockDim.x + threadIdx.x;
  int stride = gridDim.x * blockDim.x;
  for (; i < N; i += stride) atomicAdd(&cnt[ele[i]], 1);
}

__global__ void k_scan(const int* __restrict__ cnt, int* __restrict__ off) {
  __shared__ int tmp[NSEG];
  int t = threadIdx.x;
  tmp[t] = cnt[t];
  __syncthreads();
  for (int o = 1; o < NSEG; o <<= 1) {
    int add = (t >= o) ? tmp[t - o] : 0;
    __syncthreads();
    tmp[t] += add;
    __syncthreads();
  }
  off[t] = tmp[t] - cnt[t];
}

__global__ void k_scatter(const int* __restrict__ ele, const int* __restrict__ off,
                          int* __restrict__ fill, int* __restrict__ rows, int N) {
  int i = blockIdx.x * blockDim.x + threadIdx.x;
  int stride = gridDim.x * blockDim.x;
  for (; i < N; i += stride) {
    int e = ele[i];
    int p = atomicAdd(&fill[e], 1);
    rows[off[e] + p] = i;
  }
}

// ---------------- BN finalize ----------------
__global__ void k_finalize(const float* __restrict__ sum, const float* __restrict__ sumsq,
                           const float* __restrict__ g, const float* __restrict__ be,
                           float* __restrict__ A, float* __restrict__ C, int M) {
  int c = threadIdx.x;  // 512
  float m = sum[c] / (float)M;
  float v = sumsq[c] / (float)M - m * m;
  float a = g[c] * rsqrtf(v + 1e-5f);
  A[c] = a;
  C[c] = be[c] - a * m;
}

// ---------------- fused BN-apply + ReLU + segment mean (full row per block) ----------------
// One block per segment, 256 threads cover all 512 cols -> 1KB contiguous gathers.
__global__ void k_bnseg(const u16* __restrict__ hp, u16* __restrict__ h, u16* __restrict__ mean,
                        const float* __restrict__ A, const float* __restrict__ C,
                        const int* __restrict__ off, const int* __restrict__ cnt,
                        const int* __restrict__ rows) {
  int s = blockIdx.x;
  int c0 = 2 * threadIdx.x;  // 256 threads -> cols c0, c0+1
  int n = cnt[s], o = off[s];
  float a0 = A[c0], a1 = A[c0 + 1], cc0 = C[c0], cc1 = C[c0 + 1];
  float s0 = 0.f, s1 = 0.f;
#pragma unroll 2
  for (int j = 0; j < n; ++j) {
    int r = rows[o + j];
    uint32_t v = *reinterpret_cast<const uint32_t*>(&hp[(long)r * NOUT + c0]);
    float h0 = fmaxf(a0 * b2f((u16)(v & 0xffff)) + cc0, 0.f);
    float h1 = fmaxf(a1 * b2f((u16)(v >> 16)) + cc1, 0.f);
    s0 += h0; s1 += h1;
    *reinterpret_cast<uint32_t*>(&h[(long)r * NOUT + c0]) =
        ((uint32_t)f2b(h1) << 16) | (uint32_t)f2b(h0);
  }
  float inv = 1.f / fmaxf((float)n, 1.f);
  *reinterpret_cast<uint32_t*>(&mean[(long)s * NOUT + c0]) =
      ((uint32_t)f2b(s1 * inv) << 16) | (uint32_t)f2b(s0 * inv);
}

__global__ void k_final(const u16* __restrict__ hp, float* __restrict__ out,
                        const float* __restrict__ A, const float* __restrict__ C, long n4) {
  long i = blockIdx.x * (long)blockDim.x + threadIdx.x;
  long stride = (long)gridDim.x * blockDim.x;
  for (; i < n4; i += stride) {
    u16x4 v = reinterpret_cast<const u16x4*>(hp)[i];
    int c0 = (int)((i * 4) & (NOUT - 1));
    float4 a = *reinterpret_cast<const float4*>(&A[c0]);
    float4 c = *reinterpret_cast<const float4*>(&C[c0]);
    float4 o;
    o.x = fmaxf(a.x * b2f(v.x) + c.x, 0.f);
    o.y = fmaxf(a.y * b2f(v.y) + c.y, 0.f);
    o.z = fmaxf(a.z * b2f(v.z) + c.z, 0.f);
    o.w = fmaxf(a.w * b2f(v.w) + c.w, 0.f);
    reinterpret_cast<float4*>(out)[i] = o;
  }
}

// ---------------- GEMM: C[M,512] = A[M,K] @ W[K,512] ----------------
// 2-PHASE pipelined (R6 structure, best measured): dual 16KB LDS buffers; per K-tile:
//   STAGE(buf^1, t+1) -> ds_read(buf cur) -> MFMA -> __syncthreads (vmcnt(0) drain
//   lands AFTER compute, so next-tile loads fly under the MFMAs).
// Tile 128x128, BK=32, 4 waves 2x2 (64x64 each). launch_bounds(256,4): VGPR=56,
// LDS=32KB -> 4+ blocks/CU (R6's (256,3) self-capped occupancy at 40%).
// LDS [128][32] u16; conflict-free swizzle: 16B-chunk ^= (row>>1)&3 (measured 0
// conflicts), inverse-permuted GLOBAL source (m173) + XOR on ds_read (rule #21).
// A: 2 regions (k<e0 -> p0 gather?g0 else p1 gather?g1), e0 multiple of 32.
// B: wbt [512][ldb] bf16 (=W^T); k += bskip when k>=e0b. Epilogue: optional
// gather-add tab[ele[r]][col], bf16/f32 write, optional atomic col sum/sumsq
// (BN stats; linear biases dropped - they cancel in training-mode BN).
__global__ __launch_bounds__(256, 4) void k_gemm(
    const u16* p0, const u16* p1, int e0, int w0, int w1, int g0, int g1,
    const int* __restrict__ ele,
    const u16* __restrict__ wbt, int ldb, int e0b, int bskip,
    const float* __restrict__ tab, int addtab,
    u16* __restrict__ outp, float* __restrict__ outf, int wf32,
    float* __restrict__ csum, float* __restrict__ csq, int dostats,
    int M, int K) {
  __shared__ __align__(16) u16 As[2 * 4096];
  __shared__ __align__(16) u16 Bs[2 * 4096];

  int nwg = gridDim.x;
  int orig = blockIdx.x;
  // bijective XCD swizzle (m204)
  int q = nwg >> 3, r8 = nwg & 7;
  int xcd = orig & 7, loc = orig >> 3;
  int bid = (xcd < r8 ? xcd * (q + 1) : r8 * (q + 1) + (xcd - r8) * q) + loc;
  int mt = bid >> 2, ct = bid & 3;  // 4 col-tiles of same mt adjacent -> L2 A reuse
  int brow = mt * 128, bcol = ct * 128;

  int tid = (int)threadIdx.x;
  int lane = tid & 63;
  int wid = tid >> 6;
  int wr = wid >> 1, wc = wid & 1;  // 2x2 waves, 64x64 each
  int l15 = lane & 15, kg = lane >> 4;

  // staging: thread t -> row srow(+64), chunk tid&3; source chunk inverse-swizzled
  int srow = tid >> 2;                             // 0..63
  int soct = ((tid & 3) ^ ((srow >> 1) & 3)) * 8;  // u16 source col-octet

  int gr0 = brow + srow, gr1 = gr0 + 64;
  int gr0c = gr0 < M ? gr0 : M - 1;
  int gr1c = gr1 < M ? gr1 : M - 1;
  int el0 = ele[gr0c], el1 = ele[gr1c];

  const u16* a00 = p0 + (long)(g0 ? el0 : gr0c) * w0 + soct;
  const u16* a01 = p1 + (long)(g1 ? el0 : gr0c) * w1 + soct - e0;
  const u16* a10 = p0 + (long)(g0 ? el1 : gr1c) * w0 + soct;
  const u16* a11 = p1 + (long)(g1 ? el1 : gr1c) * w1 + soct - e0;

  const u16* b0p = wbt + (long)(bcol + srow) * ldb + soct;        // cols < 512
  const u16* b1p = wbt + (long)(bcol + srow + 64) * ldb + soct;

  // swizzled fragment-read offsets (u16 index within one 4096-u16 buffer)
  int xoct = (kg ^ ((l15 >> 1) & 3)) * 8;
  int aro = (wr * 64 + l15) * 32 + xoct;
  int bro = (wc * 64 + l15) * 32 + xoct;

  f32x4 acc[4][4];
#pragma unroll
  for (int m = 0; m < 4; ++m)
#pragma unroll
    for (int n = 0; n < 4; ++n)
#pragma unroll
      for (int j = 0; j < 4; ++j) acc[m][n][j] = 0.f;

  int KT = K >> 5;
  int dst = wid * 512;  // u16: per-wave linear 1KB dest region

  auto stage = [&](int tt, int buf) {
    int k0 = tt << 5;
    const u16* sa0 = k0 < e0 ? a00 : a01;
    const u16* sa1 = k0 < e0 ? a10 : a11;
    int bo = k0 + (k0 >= e0b ? bskip : 0);
    int ab = buf * 4096 + dst;
    llds16(sa0 + k0, &As[ab]);
    llds16(sa1 + k0, &As[ab + 2048]);
    llds16(b0p + bo, &Bs[ab]);
    llds16(b1p + bo, &Bs[ab + 2048]);
  };

  stage(0, 0);
  __syncthreads();

  for (int t = 0; t < KT; ++t) {
    int cur = t & 1;
    if (t + 1 < KT) stage(t + 1, cur ^ 1);
    __builtin_amdgcn_sched_barrier(0);
    const u16* Ab = &As[cur * 4096];
    const u16* Bb = &Bs[cur * 4096];
    s16x8 af[4], bf[4];
#pragma unroll
    for (int m = 0; m < 4; ++m)
      af[m] = *reinterpret_cast<const s16x8*>(&Ab[m * 512 + aro]);
#pragma unroll
    for (int n = 0; n < 4; ++n)
      bf[n] = *reinterpret_cast<const s16x8*>(&Bb[n * 512 + bro]);
#pragma unroll
    for (int m = 0; m < 4; ++m)
#pragma unroll
      for (int n = 0; n < 4; ++n)
        acc[m][n] = __builtin_amdgcn_mfma_f32_16x16x32_bf16(af[m], bf[n], acc[m][n], 0, 0, 0);
    __syncthreads();  // drain after MFMA: next-tile loads had the full phase to land
  }

  // epilogue: C layout col = lane&15, row = kg*4+j (m89-verified)
  float sums[4] = {0.f, 0.f, 0.f, 0.f}, sqs[4] = {0.f, 0.f, 0.f, 0.f};
#pragma unroll
  for (int m = 0; m < 4; ++m) {
    int row0 = brow + wr * 64 + m * 16 + kg * 4;
#pragma unroll
    for (int j = 0; j < 4; ++j) {
      int r = row0 + j;
      if (r < M) {
        long rb = (long)r * NOUT;
        long tb = addtab ? (long)ele[r] * NOUT : 0;
#pragma unroll
        for (int n = 0; n < 4; ++n) {
          int col = bcol + wc * 64 + n * 16 + l15;
          float v = acc[m][n][j];
          if (addtab) v += tab[tb + col];
          if (wf32) outf[rb + col] = v;
          else outp[rb + col] = f2b(v);
          sums[n] += v;
          sqs[n] += v * v;
        }
      }
    }
  }
  if (dostats) {
#pragma unroll
    for (int n = 0; n < 4; ++n) {
      sums[n] += __shfl_xor(sums[n], 16);
      sums[n] += __shfl_xor(sums[n], 32);
      sqs[n] += __shfl_xor(sqs[n], 16);
      sqs[n] += __shfl_xor(sqs[n], 32);
    }
    if (kg == 0) {
#pragma unroll
      for (int n = 0; n < 4; ++n) {
        int col = bcol + wc * 64 + n * 16 + l15;
        atomicAdd(&csum[col], sums[n]);
        atomicAdd(&csq[col], sqs[n]);
      }
    }
  }
}

// ---------------- host ----------------
extern "C" void kernel_launch(void* const* d_in, const int* in_sizes, int n_in,
                              void* d_out, int out_size, void* d_ws, size_t ws_size,
                              hipStream_t stream) {
  const float* x    = (const float*)d_in[0];
  const float* dist = (const float*)d_in[1];
  const int* ele    = (const int*)d_in[3];
  const float* l1w  = (const float*)d_in[4];
  const float* l1g  = (const float*)d_in[6];
  const float* l1be = (const float*)d_in[7];
  const float* l2w  = (const float*)d_in[8];
  const float* l2g  = (const float*)d_in[10];
  const float* l2be = (const float*)d_in[11];
  const float* fw   = (const float*)d_in[12];
  const float* fg   = (const float*)d_in[14];
  const float* fbe  = (const float*)d_in[15];

  int N = in_sizes[0] / 1024;  // 100000
  float* out = (float*)d_out;
  u16* xbf = (u16*)d_out;      // bf16 x overlays d_out (exact size, dead by final write)

  int MT = (N + 127) / 128;    // 782

  char* w = (char*)d_ws;
  auto alloc = [&](size_t bytes) {
    char* p = w;
    w += (bytes + 255) & ~(size_t)255;
    return p;
  };
  u16* dist_bf = (u16*)alloc((size_t)N * 256 * 2);
  u16* hp      = (u16*)alloc((size_t)N * NOUT * 2);
  u16* h       = (u16*)alloc((size_t)N * NOUT * 2);
  u16* mean    = (u16*)alloc((size_t)NSEG * NOUT * 2);
  u16* w1bt    = (u16*)alloc((size_t)NOUT * 1280 * 2);
  u16* w2bt    = (u16*)alloc((size_t)NOUT * 1280 * 2);
  u16* fbt     = (u16*)alloc((size_t)NOUT * 1024 * 2);
  float* mc2   = (float*)alloc((size_t)NSEG * NOUT * 4);
  float* mc3   = (float*)alloc((size_t)NSEG * NOUT * 4);
  float* colsum = (float*)alloc(NOUT * 4 * 2);
  float* colsumsq = colsum + NOUT;
  float* bnA   = (float*)alloc(NOUT * 4);
  float* bnC   = (float*)alloc(NOUT * 4);
  int* seg_cnt = (int*)alloc(NSEG * 4);
  int* seg_off = (int*)alloc(NSEG * 4);
  int* seg_fill = (int*)alloc(NSEG * 4);
  int* rows    = (int*)alloc((size_t)N * 4);

  size_t need = (size_t)(w - (char*)d_ws);
  if (need > ws_size) {
    fprintf(stderr, "kernel_launch: ws too small: need %zu have %zu\n", need, ws_size);
    return;
  }

  long n4x = (long)N * 1024 / 4;
  long n4d = (long)N * 256 / 4;
  long n4h = (long)N * NOUT / 4;
  int gemmGrid = MT * 4;          // 3128
  int mcGrid = (NSEG / 128) * 4;  // 32

  // casts
  k_cast<<<4096, 256, 0, stream>>>(x, xbf, n4x);
  k_cast<<<2048, 256, 0, stream>>>(dist, dist_bf, n4d);
  dim3 wt1(1280 / 32, 16), wt3(1024 / 32, 16);
  k_wtcastT<<<wt1, 256, 0, stream>>>(l1w, w1bt, 1280);
  k_wtcastT<<<wt1, 256, 0, stream>>>(l2w, w2bt, 1280);
  k_wtcastT<<<wt3, 256, 0, stream>>>(fw, fbt, 1024);

  // segment sort
  hipMemsetAsync(seg_cnt, 0, NSEG * 4, stream);
  hipMemsetAsync(seg_fill, 0, NSEG * 4, stream);
  k_hist<<<512, 256, 0, stream>>>(ele, seg_cnt, N);
  k_scan<<<1, NSEG, 0, stream>>>(seg_cnt, seg_off);
  k_scatter<<<512, 256, 0, stream>>>(ele, seg_off, seg_fill, rows, N);

  // ---- layer 1: A = [x(1024) | dist(256)], K=1280 ----
  hipMemsetAsync(colsum, 0, NOUT * 4 * 2, stream);
  k_gemm<<<gemmGrid, 256, 0, stream>>>(xbf, dist_bf, 1024, 1024, 256, 0, 0, ele,
                                       w1bt, 1280, 1280, 0, mc2, 0,
                                       hp, mc2, 0, colsum, colsumsq, 1, N, 1280);
  k_finalize<<<1, NOUT, 0, stream>>>(colsum, colsumsq, l1g, l1be, bnA, bnC, N);
  k_bnseg<<<NSEG, 256, 0, stream>>>(hp, h, mean, bnA, bnC, seg_off, seg_cnt, rows);

  // ---- layer 2: mc2 = mean @ W2[512:1024); A = [h(512) | dist(256)], K=768 ----
  k_gemm<<<mcGrid, 256, 0, stream>>>(mean, mean, 512, 512, 512, 0, 0, ele,
                                     w2bt + 512, 1280, 512, 0, mc2, 0,
                                     hp, mc2, 1, colsum, colsumsq, 0, NSEG, 512);
  hipMemsetAsync(colsum, 0, NOUT * 4 * 2, stream);
  k_gemm<<<gemmGrid, 256, 0, stream>>>(h, dist_bf, 512, 512, 256, 0, 0, ele,
                                       w2bt, 1280, 512, 512, mc2, 1,
                                       hp, mc2, 0, colsum, colsumsq, 1, N, 768);
  k_finalize<<<1, NOUT, 0, stream>>>(colsum, colsumsq, l2g, l2be, bnA, bnC, N);
  k_bnseg<<<NSEG, 256, 0, stream>>>(hp, h, mean, bnA, bnC, seg_off, seg_cnt, rows);

  // ---- final layer: mc3 = mean @ F[512:1024); A = h, K=512 ----
  k_gemm<<<mcGrid, 256, 0, stream>>>(mean, mean, 512, 512, 512, 0, 0, ele,
                                     fbt + 512, 1024, 512, 0, mc3, 0,
                                     hp, mc3, 1, colsum, colsumsq, 0, NSEG, 512);
  hipMemsetAsync(colsum, 0, NOUT * 4 * 2, stream);
  k_gemm<<<gemmGrid, 256, 0, stream>>>(h, h, 512, 512, 512, 0, 0, ele,
                                       fbt, 1024, 512, 0, mc3, 1,
                                       hp, mc3, 0, colsum, colsumsq, 1, N, 512);
  k_finalize<<<1, NOUT, 0, stream>>>(colsum, colsumsq, fg, fbe, bnA, bnC, N);
  k_final<<<4096, 256, 0, stream>>>(hp, out, bnA, bnC, n4h);
}